// Round 4
// baseline (224.040 us; speedup 1.0000x reference)
//
#include <hip/hip_runtime.h>
#include <hip/hip_bf16.h>

#define B_ 16
#define S_ 4096
#define D_ 64
#define H_ 8
#define NB_ 64          // n_buckets
#define M_ 64           // bucket_size
#define CHUNKS_ 512     // per batch = H_*NB_
#define NC_ 4           // chunks per attn block (sliding window)
#define GRPS_ 128       // chunk groups per batch = CHUNKS_/NC_
#define LOG2E 1.4426950408889634f
#define LN2 0.6931471805599453f

#define QS_ 72          // K LDS row stride (shorts)
#define VTS_ 68         // V^T row stride (dwords): 64 data (32 cur + 32 prev... cur=[0,32), prev=[32,64)) + 4 pad
// Ps staging aliases the V^T prev+pad tail: shorts [row*136 + 64, row*136 + 136)

typedef short short8 __attribute__((ext_vector_type(8)));
typedef short short4v __attribute__((ext_vector_type(4)));
typedef float floatx4 __attribute__((ext_vector_type(4)));

__device__ __forceinline__ float bf2f(unsigned short s) {
    return __uint_as_float(((unsigned int)s) << 16);
}
__device__ __forceinline__ unsigned pk2(float a, float b) {
    __hip_bfloat162 h = __float22bfloat162_rn(make_float2(a, b));
    return *(unsigned*)&h;
}
__device__ __forceinline__ unsigned short f2bf1(float x) {
    return (unsigned short)pk2(x, x);
}
__device__ __forceinline__ uint4 pack8(float4 a, float4 b) {
    uint4 u;
    u.x = pk2(a.x, a.y); u.y = pk2(a.z, a.w);
    u.z = pk2(b.x, b.y); u.w = pk2(b.z, b.w);
    return u;
}
__device__ __forceinline__ short4v mk4(unsigned lo, unsigned hi) {
    uint2 t = make_uint2(lo, hi);
    return *(short4v*)&t;
}

// ---------------- K1: hashing (round-6 version, FROZEN FP ORDER) ----------------
__global__ void __launch_bounds__(256)
hash_kernel(const float* __restrict__ qk,
            const float* __restrict__ rot,
            int* __restrict__ bucket) {
    int bh = blockIdx.x >> 3;      // (b*H + h)
    int tc = blockIdx.x & 7;       // 512-token chunk
    int h = bh & 7;
    int b = bh >> 3;

    __shared__ float rl[64 * 32];
    #pragma unroll
    for (int k = 0; k < 8; k++) {
        int e = k * 256 + threadIdx.x;
        rl[e] = rot[(e >> 5) * (H_ * 32) + h * 32 + (e & 31)];
    }
    __syncthreads();

    const int t0 = tc * 512 + threadIdx.x;   // tokens t0, t0+256

    const float4* qrow0 = (const float4*)(qk + ((size_t)(b * S_ + t0)) * D_);
    const float4* qrow1 = (const float4*)(qk + ((size_t)(b * S_ + t0 + 256)) * D_);

    float acc[2][32];
    #pragma unroll
    for (int u = 0; u < 2; u++)
        #pragma unroll
        for (int i = 0; i < 32; i++) acc[u][i] = 0.f;

    for (int k = 0; k < 16; k++) {
        float4 x0 = qrow0[k];
        float4 x1 = qrow1[k];
        const float* r0 = &rl[(4 * k + 0) * 32];
        const float* r1 = &rl[(4 * k + 1) * 32];
        const float* r2 = &rl[(4 * k + 2) * 32];
        const float* r3 = &rl[(4 * k + 3) * 32];
        #pragma unroll
        for (int i = 0; i < 32; i++) {
            float a0 = r0[i], a1 = r1[i], a2 = r2[i], a3 = r3[i];
            acc[0][i] += x0.x * a0 + x0.y * a1 + x0.z * a2 + x0.w * a3;
            acc[1][i] += x1.x * a0 + x1.y * a1 + x1.z * a2 + x1.w * a3;
        }
    }

    #pragma unroll
    for (int u = 0; u < 2; u++) {
        float best = acc[u][0];
        int bi = 0;
        #pragma unroll
        for (int i = 1; i < 32; i++)
            if (acc[u][i] > best) { best = acc[u][i]; bi = i; }
        #pragma unroll
        for (int i = 0; i < 32; i++) {
            float nv = -acc[u][i];
            if (nv > best) { best = nv; bi = 32 + i; }
        }
        bucket[bh * S_ + t0 + 256 * u] = bi;
    }
}

// ---------------- K2: parallel stable counting sort (+undo) ----------------
__global__ void __launch_bounds__(256)
sort_kernel(const int* __restrict__ bucket,
            int* __restrict__ st,
            int* __restrict__ ud) {
    const int bh = blockIdx.x;
    const int t = threadIdx.x;
    __shared__ int bl[S_];             // 16 KB
    __shared__ int cnt[256 * 64];      // 64 KB: cnt[group*64 + bucket]
    __shared__ int qsum[64 * 4];       // per-bucket quarter sums
    __shared__ int tot[64];
    __shared__ int start[64];

    const int base = bh * S_;
    #pragma unroll
    for (int i = 0; i < 16; i++) bl[i * 256 + t] = bucket[base + i * 256 + t];
    #pragma unroll
    for (int i = 0; i < 64; i++) cnt[t * 64 + i] = 0;
    __syncthreads();

    // A: per-group histogram (serial 16)
    #pragma unroll
    for (int j = 0; j < 16; j++) cnt[t * 64 + bl[t * 16 + j]]++;
    __syncthreads();

    // B1: quarter sums
    {
        const int bk = t & 63, q = t >> 6;
        int s = 0;
        for (int g = q * 64; g < q * 64 + 64; g++) s += cnt[g * 64 + bk];
        qsum[bk * 4 + q] = s;
    }
    __syncthreads();

    // B2: bucket totals + global starts
    if (t < 64) tot[t] = qsum[t * 4] + qsum[t * 4 + 1] + qsum[t * 4 + 2] + qsum[t * 4 + 3];
    __syncthreads();
    if (t == 0) {
        int run = 0;
        for (int bk = 0; bk < 64; bk++) { start[bk] = run; run += tot[bk]; }
    }
    __syncthreads();

    // B3: exclusive running prefix (bucket-major, group-minor)
    {
        const int bk = t & 63, q = t >> 6;
        int run = start[bk];
        for (int qq = 0; qq < 4; qq++) if (qq < q) run += qsum[bk * 4 + qq];
        for (int g = q * 64; g < q * 64 + 64; g++) {
            int c = cnt[g * 64 + bk];
            cnt[g * 64 + bk] = run;
            run += c;
        }
    }
    __syncthreads();

    // C: stable placement; record inverse in bl
    #pragma unroll
    for (int j = 0; j < 16; j++) {
        int tok = t * 16 + j;
        int bk = bl[tok];
        int p = cnt[t * 64 + bk]++;
        st[base + p] = tok;
        bl[tok] = p;
    }
    __syncthreads();

    // D: coalesced undo dump
    #pragma unroll
    for (int i = 0; i < 16; i++) ud[base + i * 256 + t] = bl[i * 256 + t];
}

// ---------------- K3: MFMA chunked attention, NC_-chunk sliding window ----------------
// Round 11: each block processes NC_=4 consecutive chunks of one (b,h).
// Staging passes: 5 per block vs 8 (2 per chunk before) -> x0.625 staging VALU;
// V^T restage: 1 half/chunk vs 2 (prev half carried by a 32B/thread LDS copy).
// Slots keep identical meaning (cur=0..63, prev=64..127) via bitwise copy ->
// arithmetic is BIT-IDENTICAL to the round-3 kernel (absmax must not change).
// V^T gets its own region (K survives across iterations now); Ps staging
// aliases the V^T prev+pad tail (dead at epilogue), guarded by barrier D.
// LDS = 18432(K) + 17408(VT) + 768 = ~36.6 KB -> 4 blocks/CU, 16 waves/CU.
__global__ void __launch_bounds__(256, 4)
attn_kernel(const float* __restrict__ qk,
            const float* __restrict__ v,
            const int* __restrict__ st,
            unsigned short* __restrict__ ou,   // bf16 (B,H,S,D) SORTED order
            float* __restrict__ lse_u) {       // (B,H,S) SORTED order
    const int tid = threadIdx.x;
    const int gid = blockIdx.x;                     // 0..B_*GRPS_-1 = 0..2047
    const int gc = (gid & 7) * 256 + (gid >> 3);    // XCD-contiguous groups
    const int b = gc >> 7;
    const int g = gc & 127;                         // chunk group within batch
    const int h = g >> 4;                           // 16 groups per h (4|64)
    const int c0 = g * NC_;

    __shared__ alignas(16) unsigned short Ks[128 * QS_];  // normalized K rows
    __shared__ alignas(16) unsigned VT[64 * VTS_];        // V^T (feature-major)
    __shared__ int tkv[128];
    __shared__ float bounds[64];

    const int stok = tid >> 2;                 // 0..63 token slot
    const int q4 = tid & 3;                    // 16-feature slice
    const int lane = tid & 63;
    const int w = tid >> 6;
    const int lm = lane & 15;
    const int lq = lane >> 4;

    const size_t stBase = (size_t)b * (CHUNKS_ * M_);
    const size_t qkBase = (size_t)b * S_;
    const size_t oBaseBH = (size_t)(b * H_ + h) * S_;

    #pragma unroll 1
    for (int ci = 0; ci < NC_; ci++) {
        const int cc = c0 + ci;

        // ---- early global gathers for cur (and prev on iter 0) ----
        const int pos0 = st[stBase + cc * 64 + stok];
        const float4* src = (const float4*)(qk + (qkBase + pos0) * 64) + q4 * 4;
        float4 x0 = src[0], x1 = src[1], x2 = src[2], x3 = src[3];
        const float4* vsrc = (const float4*)(v + (qkBase + pos0) * 64) + q4 * 4;
        float4 y0 = vsrc[0], y1 = vsrc[1], y2 = vsrc[2], y3 = vsrc[3];

        float4 xp0, xp1, xp2, xp3, yp0, yp1, yp2, yp3;
        int pos1 = 0;
        if (ci == 0) {
            pos1 = st[stBase + ((cc - 1) & 511) * 64 + stok];
            const float4* srcp = (const float4*)(qk + (qkBase + pos1) * 64) + q4 * 4;
            xp0 = srcp[0]; xp1 = srcp[1]; xp2 = srcp[2]; xp3 = srcp[3];
            const float4* vsp = (const float4*)(v + (qkBase + pos1) * 64) + q4 * 4;
            yp0 = vsp[0]; yp1 = vsp[1]; yp2 = vsp[2]; yp3 = vsp[3];
        }

        if (ci > 0) {
            __syncthreads();   // A: prior iter's LDS reads/Ps done before overwrite
            // ---- copy cur -> prev (bitwise; 32B K + 32B VT per thread) ----
            uint4 ka = *(const uint4*)&Ks[stok * QS_ + q4 * 16];
            uint4 kb = *(const uint4*)&Ks[stok * QS_ + q4 * 16 + 8];
            uint4 va = *(const uint4*)&VT[stok * VTS_ + q4 * 8];
            uint4 vb2 = *(const uint4*)&VT[stok * VTS_ + q4 * 8 + 4];
            int tcopy = tkv[stok];
            *(uint4*)&Ks[(64 + stok) * QS_ + q4 * 16] = ka;
            *(uint4*)&Ks[(64 + stok) * QS_ + q4 * 16 + 8] = kb;
            *(uint4*)&VT[stok * VTS_ + 32 + q4 * 8] = va;
            *(uint4*)&VT[stok * VTS_ + 32 + q4 * 8 + 4] = vb2;
            if (q4 == 0) tkv[64 + stok] = tcopy;
            __syncthreads();   // B: copy reads done before cur slots overwritten
        }

        // ---- stage cur: normalized K -> Ks[0..63], V^T -> VT cols [0,32) ----
        {
            float ss = x0.x*x0.x + x0.y*x0.y + x0.z*x0.z + x0.w*x0.w
                     + x1.x*x1.x + x1.y*x1.y + x1.z*x1.z + x1.w*x1.w
                     + x2.x*x2.x + x2.y*x2.y + x2.z*x2.z + x2.w*x2.w
                     + x3.x*x3.x + x3.y*x3.y + x3.z*x3.z + x3.w*x3.w;
            ss += __shfl_xor(ss, 1);
            ss += __shfl_xor(ss, 2);
            float nrm = sqrtf(ss);
            float rn = 1.f / fmaxf(nrm, 1e-12f);

            float4 k0 = make_float4(x0.x*rn, x0.y*rn, x0.z*rn, x0.w*rn);
            float4 k1 = make_float4(x1.x*rn, x1.y*rn, x1.z*rn, x1.w*rn);
            float4 k2 = make_float4(x2.x*rn, x2.y*rn, x2.z*rn, x2.w*rn);
            float4 k3 = make_float4(x3.x*rn, x3.y*rn, x3.z*rn, x3.w*rn);
            *(uint4*)&Ks[stok * QS_ + q4 * 16]     = pack8(k0, k1);
            *(uint4*)&Ks[stok * QS_ + q4 * 16 + 8] = pack8(k2, k3);

            unsigned vp[8];
            vp[0] = pk2(y0.x, y0.y); vp[1] = pk2(y0.z, y0.w);
            vp[2] = pk2(y1.x, y1.y); vp[3] = pk2(y1.z, y1.w);
            vp[4] = pk2(y2.x, y2.y); vp[5] = pk2(y2.z, y2.w);
            vp[6] = pk2(y3.x, y3.y); vp[7] = pk2(y3.z, y3.w);

            if (q4 == 0) { tkv[stok] = pos0; bounds[stok] = nrm * 0.125f; }

            const int par = stok & 1;
            const int pdw = (stok >> 1) ^ (q4 << 3);
            #pragma unroll
            for (int i = 0; i < 8; i++) {
                unsigned mine = vp[i];
                unsigned theirs = (unsigned)__shfl_xor((int)mine, 4);
                unsigned outw = par ? ((theirs >> 16) | (mine & 0xFFFF0000u))
                                    : ((mine & 0xFFFFu) | (theirs << 16));
                VT[(q4 * 16 + 2 * i + par) * VTS_ + pdw] = outw;
            }
        }

        if (ci == 0) {
            // ---- stage prev: slots 64..127, VT cols [32,64) ----
            float ss = xp0.x*xp0.x + xp0.y*xp0.y + xp0.z*xp0.z + xp0.w*xp0.w
                     + xp1.x*xp1.x + xp1.y*xp1.y + xp1.z*xp1.z + xp1.w*xp1.w
                     + xp2.x*xp2.x + xp2.y*xp2.y + xp2.z*xp2.z + xp2.w*xp2.w
                     + xp3.x*xp3.x + xp3.y*xp3.y + xp3.z*xp3.z + xp3.w*xp3.w;
            ss += __shfl_xor(ss, 1);
            ss += __shfl_xor(ss, 2);
            float nrm = sqrtf(ss);
            float rn = 1.f / fmaxf(nrm, 1e-12f);

            float4 k0 = make_float4(xp0.x*rn, xp0.y*rn, xp0.z*rn, xp0.w*rn);
            float4 k1 = make_float4(xp1.x*rn, xp1.y*rn, xp1.z*rn, xp1.w*rn);
            float4 k2 = make_float4(xp2.x*rn, xp2.y*rn, xp2.z*rn, xp2.w*rn);
            float4 k3 = make_float4(xp3.x*rn, xp3.y*rn, xp3.z*rn, xp3.w*rn);
            *(uint4*)&Ks[(64 + stok) * QS_ + q4 * 16]     = pack8(k0, k1);
            *(uint4*)&Ks[(64 + stok) * QS_ + q4 * 16 + 8] = pack8(k2, k3);

            unsigned vp[8];
            vp[0] = pk2(yp0.x, yp0.y); vp[1] = pk2(yp0.z, yp0.w);
            vp[2] = pk2(yp1.x, yp1.y); vp[3] = pk2(yp1.z, yp1.w);
            vp[4] = pk2(yp2.x, yp2.y); vp[5] = pk2(yp2.z, yp2.w);
            vp[6] = pk2(yp3.x, yp3.y); vp[7] = pk2(yp3.z, yp3.w);

            if (q4 == 0) tkv[64 + stok] = pos1;

            const int par = stok & 1;
            const int pdw = (32 + (stok >> 1)) ^ (q4 << 3);
            #pragma unroll
            for (int i = 0; i < 8; i++) {
                unsigned mine = vp[i];
                unsigned theirs = (unsigned)__shfl_xor((int)mine, 4);
                unsigned outw = par ? ((theirs >> 16) | (mine & 0xFFFF0000u))
                                    : ((mine & 0xFFFFu) | (theirs << 16));
                VT[(q4 * 16 + 2 * i + par) * VTS_ + pdw] = outw;
            }
        }
        __syncthreads();   // C: staging visible

        // ---- S^T = K * Q^T ----
        const int   tq  = tkv[w * 16 + lm];
        const float bnd = bounds[w * 16 + lm];
        const float bl2 = bnd * LOG2E;

        const short8 bq0 = *(const short8*)&Ks[(w * 16 + lm) * QS_ + lq * 8];
        const short8 bq1 = *(const short8*)&Ks[(w * 16 + lm) * QS_ + 32 + lq * 8];
        floatx4 C[8];
        #pragma unroll
        for (int nt = 0; nt < 8; nt++) {
            const short8 a0 = *(const short8*)&Ks[(nt * 16 + lm) * QS_ + lq * 8];
            const short8 a1 = *(const short8*)&Ks[(nt * 16 + lm) * QS_ + 32 + lq * 8];
            floatx4 c = {0.f, 0.f, 0.f, 0.f};
            c = __builtin_amdgcn_mfma_f32_16x16x32_bf16(a0, bq0, c, 0, 0, 0);
            c = __builtin_amdgcn_mfma_f32_16x16x32_bf16(a1, bq1, c, 0, 0, 0);
            C[nt] = c;
        }

        // ---- mask + exp -> P in registers as x16 A-frags ----
        float lsum = 0.f, ns = 0.f;
        short4v pa[8];
        #pragma unroll
        for (int nt = 0; nt < 8; nt++) {
            int4 tki = *(const int4*)&tkv[nt * 16 + lq * 4];
            float p0 = (tki.x < tq) ? exp2f((C[nt][0] - 1.f) * bl2) : 0.f;
            float p1 = (tki.y < tq) ? exp2f((C[nt][1] - 1.f) * bl2) : 0.f;
            float p2 = (tki.z < tq) ? exp2f((C[nt][2] - 1.f) * bl2) : 0.f;
            float p3 = (tki.w < tq) ? exp2f((C[nt][3] - 1.f) * bl2) : 0.f;
            ns += (tki.x == tq) ? 1.f : 0.f;
            ns += (tki.y == tq) ? 1.f : 0.f;
            ns += (tki.z == tq) ? 1.f : 0.f;
            ns += (tki.w == tq) ? 1.f : 0.f;
            lsum += (p0 + p1) + (p2 + p3);
            pa[nt] = mk4(pk2(p0, p1), pk2(p2, p3));
        }
        lsum += __shfl_xor(lsum, 16);
        lsum += __shfl_xor(lsum, 32);
        ns   += __shfl_xor(ns, 16);
        ns   += __shfl_xor(ns, 32);

        // ---- PV (V^T stable since barrier C; no barrier needed) ----
        floatx4 O[4];
        #pragma unroll
        for (int nt2 = 0; nt2 < 4; nt2++) O[nt2] = floatx4{0.f, 0.f, 0.f, 0.f};
        #pragma unroll
        for (int kt = 0; kt < 8; kt++) {
            #pragma unroll
            for (int nt2 = 0; nt2 < 4; nt2++) {
                const short4v vb = *(const short4v*)&VT[(nt2 * 16 + lm) * VTS_
                                    + ((kt ^ nt2) * 8 + lq * 2)];
                O[nt2] = __builtin_amdgcn_mfma_f32_16x16x16bf16_1k(pa[kt], vb, O[nt2], 0, 0, 0);
            }
        }
        __syncthreads();   // D: all PV reads of VT done before Ps-alias writes

        // ---- epilogue (Ps aliased onto VT row tails; sorted coalesced stores) ----
        unsigned short* PsS = (unsigned short*)VT;   // Ps(row,i) = PsS[row*136 + 64 + i]
        const int spB = (cc & 63) * 64;
        #pragma unroll
        for (int r = 0; r < 4; r++) {
            int qrow = w * 16 + lq * 4 + r;
            float s = __shfl(lsum, lq * 4 + r);
            float invl;
            if (s > 0.f) {
                invl = 1.f / s;
            } else {
                invl = 1.f;
                int pos = tkv[qrow];
                #pragma unroll
                for (int nt2 = 0; nt2 < 4; nt2++)
                    O[nt2][r] = v[(qkBase + pos) * 64 + nt2 * 16 + lm];
            }
            #pragma unroll
            for (int nt2 = 0; nt2 < 4; nt2++)
                PsS[qrow * 136 + 64 + nt2 * 16 + lm] = f2bf1(O[nt2][r] * invl);
        }
        if (lq == 0) {
            float lse = (lsum > 0.f) ? (bnd + log2f(lsum) * LN2)
                                     : (-50000.f + logf(ns));
            lse_u[oBaseBH + spB + w * 16 + lm] = lse;
        }
        {
            int rrow = lane >> 2;
            int seg = lane & 3;
            int qrow = w * 16 + rrow;
            uint4 u0 = *(uint4*)&PsS[qrow * 136 + 64 + seg * 16];
            uint4 u1 = *(uint4*)&PsS[qrow * 136 + 64 + seg * 16 + 8];
            unsigned short* dst = ou + (oBaseBH + spB + qrow) * 64 + seg * 16;
            *(uint4*)dst = u0;
            *(uint4*)(dst + 8) = u1;
        }
    }
}

// ---------------- K4: combine hash rounds (gather via undo-sort) ----------------
__global__ void combine_kernel(const unsigned short* __restrict__ ou,
                               const float* __restrict__ lse_u,
                               const int* __restrict__ ud,
                               float* __restrict__ out) {
    int idx = blockIdx.x * 256 + threadIdx.x;
    int f4 = idx & 15;
    int t = (idx >> 4) & (S_ - 1);
    int b = idx >> 16;

    int pp[H_];
    float le[H_];
    float m = -3.4e38f;
    #pragma unroll
    for (int h = 0; h < H_; h++) {
        size_t sl = (size_t)(b * H_ + h) * S_;
        int p = ud[sl + t];
        pp[h] = p;
        le[h] = lse_u[sl + p];
        m = fmaxf(m, le[h]);
    }
    float s = 0.f, e[H_];
    #pragma unroll
    for (int h = 0; h < H_; h++) {
        e[h] = exp2f((le[h] - m) * LOG2E);
        s += e[h];
    }
    float4 o = make_float4(0.f, 0.f, 0.f, 0.f);
    #pragma unroll
    for (int h = 0; h < H_; h++) {
        uint2 u = *(const uint2*)(ou + ((size_t)((b * H_ + h) * S_ + pp[h])) * 64 + f4 * 4);
        o.x += e[h] * bf2f((unsigned short)(u.x & 0xFFFFu));
        o.y += e[h] * bf2f((unsigned short)(u.x >> 16));
        o.z += e[h] * bf2f((unsigned short)(u.y & 0xFFFFu));
        o.w += e[h] * bf2f((unsigned short)(u.y >> 16));
    }
    float inv = 1.f / s;
    ((float4*)out)[idx] = make_float4(o.x * inv, o.y * inv, o.z * inv, o.w * inv);
}

extern "C" void kernel_launch(void* const* d_in, const int* in_sizes, int n_in,
                              void* d_out, int out_size, void* d_ws, size_t ws_size,
                              hipStream_t stream) {
    const float* qk  = (const float*)d_in[0];
    const float* v   = (const float*)d_in[1];
    const float* rot = (const float*)d_in[2];
    float* out = (float*)d_out;

    char* ws = (char*)d_ws;
    int* bucket  = (int*)(ws);                       // 2 MB; reused as undo
    int* st      = (int*)(ws + 2097152);
    float* lse_u = (float*)(ws + 4194304);
    unsigned short* ou = (unsigned short*)(ws + 6291456);   // bf16, 67 MB
    int* undo = bucket;

    hash_kernel<<<dim3(B_ * H_ * (S_ / 512)), dim3(256), 0, stream>>>(qk, rot, bucket);
    sort_kernel<<<dim3(B_ * H_), dim3(256), 0, stream>>>(bucket, st, undo);
    attn_kernel<<<dim3(B_ * GRPS_), dim3(256), 0, stream>>>(qk, v, st, ou, lse_u);
    combine_kernel<<<dim3((B_ * S_ * 16) / 256), dim3(256), 0, stream>>>(ou, lse_u, undo, out);
}

// Round 5
// 206.830 us; speedup vs baseline: 1.0832x; 1.0832x over previous
//
#include <hip/hip_runtime.h>
#include <hip/hip_bf16.h>

#define B_ 16
#define S_ 4096
#define D_ 64
#define H_ 8
#define NB_ 64          // n_buckets
#define M_ 64           // bucket_size
#define CHUNKS_ 512     // per batch = H_*NB_
#define LOG2E 1.4426950408889634f
#define LN2 0.6931471805599453f

#define QS_ 72          // K LDS row stride (shorts)
#define VTS_ 68         // V^T row stride (dwords)
#define PS_ 72          // O-transpose staging row stride (shorts)

typedef short short8 __attribute__((ext_vector_type(8)));
typedef short short4v __attribute__((ext_vector_type(4)));
typedef float floatx4 __attribute__((ext_vector_type(4)));

__device__ __forceinline__ float bf2f(unsigned short s) {
    return __uint_as_float(((unsigned int)s) << 16);
}
__device__ __forceinline__ unsigned pk2(float a, float b) {
    __hip_bfloat162 h = __float22bfloat162_rn(make_float2(a, b));
    return *(unsigned*)&h;
}
__device__ __forceinline__ unsigned short f2bf1(float x) {
    return (unsigned short)pk2(x, x);
}
__device__ __forceinline__ uint4 pack8(float4 a, float4 b) {
    uint4 u;
    u.x = pk2(a.x, a.y); u.y = pk2(a.z, a.w);
    u.z = pk2(b.x, b.y); u.w = pk2(b.z, b.w);
    return u;
}
__device__ __forceinline__ short4v mk4(unsigned lo, unsigned hi) {
    uint2 t = make_uint2(lo, hi);
    return *(short4v*)&t;
}

// ---------------- K1: hashing, i-sliced (round 12) ----------------
// Thread = (token-group g, slice s): 4 tokens x 16 rotation-indices.
// Per-element FMA expression/order identical to the frozen round-6 form ->
// bit-identical sums; LDS R-reads per token drop 4x (the round-4 analysis
// put hash at up to ~40us LDS-issue-bound). Argmax recombined across the
// two slices via shfl_xor(1) with exact first-index tie-break semantics.
__global__ void __launch_bounds__(256)
hash_kernel(const float* __restrict__ qk,
            const float* __restrict__ rot,
            int* __restrict__ bucket) {
    int bh = blockIdx.x >> 3;      // (b*H + h)
    int tc = blockIdx.x & 7;       // 512-token chunk
    int h = bh & 7;
    int b = bh >> 3;

    __shared__ float rl[64 * 32];
    #pragma unroll
    for (int k = 0; k < 8; k++) {
        int e = k * 256 + threadIdx.x;
        rl[e] = rot[(e >> 5) * (H_ * 32) + h * 32 + (e & 31)];
    }
    __syncthreads();

    const int g = threadIdx.x >> 1;        // 0..127 token group
    const int s = threadIdx.x & 1;         // i-slice (cols s*16..s*16+15)
    const int s16 = s * 16;
    const int t0 = tc * 512 + g;           // tokens t0 + 128*j, j=0..3

    const float4* qr0 = (const float4*)(qk + ((size_t)(b * S_ + t0)) * D_);
    const float4* qr1 = (const float4*)(qk + ((size_t)(b * S_ + t0 + 128)) * D_);
    const float4* qr2 = (const float4*)(qk + ((size_t)(b * S_ + t0 + 256)) * D_);
    const float4* qr3 = (const float4*)(qk + ((size_t)(b * S_ + t0 + 384)) * D_);

    float acc[4][16];
    #pragma unroll
    for (int u = 0; u < 4; u++)
        #pragma unroll
        for (int i = 0; i < 16; i++) acc[u][i] = 0.f;

    for (int k = 0; k < 16; k++) {
        float4 x0 = qr0[k];
        float4 x1 = qr1[k];
        float4 x2 = qr2[k];
        float4 x3 = qr3[k];
        const float* r0 = &rl[(4 * k + 0) * 32 + s16];
        const float* r1 = &rl[(4 * k + 1) * 32 + s16];
        const float* r2 = &rl[(4 * k + 2) * 32 + s16];
        const float* r3 = &rl[(4 * k + 3) * 32 + s16];
        #pragma unroll
        for (int i = 0; i < 16; i++) {
            float a0 = r0[i], a1 = r1[i], a2 = r2[i], a3 = r3[i];
            acc[0][i] += x0.x * a0 + x0.y * a1 + x0.z * a2 + x0.w * a3;
            acc[1][i] += x1.x * a0 + x1.y * a1 + x1.z * a2 + x1.w * a3;
            acc[2][i] += x2.x * a0 + x2.y * a1 + x2.z * a2 + x2.w * a3;
            acc[3][i] += x3.x * a0 + x3.y * a1 + x3.z * a2 + x3.w * a3;
        }
    }

    #pragma unroll
    for (int u = 0; u < 4; u++) {
        float best = acc[u][0];
        int bi = s16;
        #pragma unroll
        for (int i = 1; i < 16; i++)
            if (acc[u][i] > best) { best = acc[u][i]; bi = s16 + i; }
        #pragma unroll
        for (int i = 0; i < 16; i++) {
            float nv = -acc[u][i];
            if (nv > best) { best = nv; bi = 32 + s16 + i; }
        }
        // combine the two slices; keep earliest index on exact ties
        float ov = __shfl_xor(best, 1);
        int obi = __shfl_xor(bi, 1);
        if (ov > best || (ov == best && obi < bi)) { best = ov; bi = obi; }
        if (s == 0) bucket[bh * S_ + t0 + 128 * u] = bi;
    }
}

// ---------------- K2: parallel stable counting sort (+undo) ----------------
// Round 12: stable placement goes to LDS (stl) and st is dumped coalesced,
// removing the ~16x granule amplification of the 4B scattered st writes.
__global__ void __launch_bounds__(256)
sort_kernel(const int* __restrict__ bucket,
            int* __restrict__ st,
            int* __restrict__ ud) {
    const int bh = blockIdx.x;
    const int t = threadIdx.x;
    __shared__ int bl[S_];             // 16 KB
    __shared__ int stl[S_];            // 16 KB (sorted tokens, coalesced dump)
    __shared__ int cnt[256 * 64];      // 64 KB: cnt[group*64 + bucket]
    __shared__ int qsum[64 * 4];       // per-bucket quarter sums
    __shared__ int tot[64];
    __shared__ int start[64];

    const int base = bh * S_;
    #pragma unroll
    for (int i = 0; i < 16; i++) bl[i * 256 + t] = bucket[base + i * 256 + t];
    #pragma unroll
    for (int i = 0; i < 64; i++) cnt[t * 64 + i] = 0;
    __syncthreads();

    // A: per-group histogram (serial 16)
    #pragma unroll
    for (int j = 0; j < 16; j++) cnt[t * 64 + bl[t * 16 + j]]++;
    __syncthreads();

    // B1: quarter sums
    {
        const int bk = t & 63, q = t >> 6;
        int s = 0;
        for (int g = q * 64; g < q * 64 + 64; g++) s += cnt[g * 64 + bk];
        qsum[bk * 4 + q] = s;
    }
    __syncthreads();

    // B2: bucket totals + global starts
    if (t < 64) tot[t] = qsum[t * 4] + qsum[t * 4 + 1] + qsum[t * 4 + 2] + qsum[t * 4 + 3];
    __syncthreads();
    if (t == 0) {
        int run = 0;
        for (int bk = 0; bk < 64; bk++) { start[bk] = run; run += tot[bk]; }
    }
    __syncthreads();

    // B3: exclusive running prefix (bucket-major, group-minor)
    {
        const int bk = t & 63, q = t >> 6;
        int run = start[bk];
        for (int qq = 0; qq < 4; qq++) if (qq < q) run += qsum[bk * 4 + qq];
        for (int g = q * 64; g < q * 64 + 64; g++) {
            int c = cnt[g * 64 + bk];
            cnt[g * 64 + bk] = run;
            run += c;
        }
    }
    __syncthreads();

    // C: stable placement into LDS; record inverse in bl
    #pragma unroll
    for (int j = 0; j < 16; j++) {
        int tok = t * 16 + j;
        int bk = bl[tok];
        int p = cnt[t * 64 + bk]++;
        stl[p] = tok;
        bl[tok] = p;
    }
    __syncthreads();

    // D: coalesced dumps
    #pragma unroll
    for (int i = 0; i < 16; i++) {
        st[base + i * 256 + t] = stl[i * 256 + t];
        ud[base + i * 256 + t] = bl[i * 256 + t];
    }
}

// ---------------- K3: MFMA chunked attention (round-3 exact, PROVEN 80.5us) ----------------
// Round-4's NC=4 sliding window regressed (barriers+dependent gathers in the
// loop -> latency-bound, VALUBusy 77->56). Keep the 1-chunk/block structure.
__global__ void __launch_bounds__(256, 5)
attn_kernel(const float* __restrict__ qk,
            const float* __restrict__ v,
            const int* __restrict__ st,
            unsigned short* __restrict__ ou,   // bf16 (B,H,S,D) SORTED order
            float* __restrict__ lse_u) {       // (B,H,S) SORTED order
    const int tid = threadIdx.x;
    const int gid = blockIdx.x;
    const int gc = (gid & 7) * 1024 + (gid >> 3);   // XCD-contiguous global chunk
    const int b = gc >> 9;
    const int cc = gc & 511;
    const int prev = (cc - 1) & 511;
    const int h = cc >> 6;

    __shared__ alignas(16) unsigned short KV[128 * QS_];  // K rows, then V^T
    __shared__ alignas(16) unsigned short Ps[64 * PS_];   // O transpose staging
    __shared__ int tkv[128];
    __shared__ float bounds[64];

    const int stBase = b * (CHUNKS_ * M_);
    if (tid < 128) tkv[tid] = st[stBase + (tid < 64 ? cc : prev) * 64 + (tid & 63)];
    __syncthreads();

    const int stok = tid >> 2;                 // 0..63 (token within pass)
    const int q4 = tid & 3;                    // 16-feature slice

    // ---- stage normalized K; hold V (packed bf16) in regs ----
    unsigned vpk[2][8];
    #pragma unroll
    for (int p = 0; p < 2; p++) {
        int tok = p * 64 + stok;
        int pos = tkv[tok];
        const float4* src = (const float4*)(qk + (size_t)(b * S_ + pos) * 64) + q4 * 4;
        float4 x0 = src[0], x1 = src[1], x2 = src[2], x3 = src[3];
        const float4* vsrc = (const float4*)(v + (size_t)(b * S_ + pos) * 64) + q4 * 4;
        float4 y0 = vsrc[0], y1 = vsrc[1], y2 = vsrc[2], y3 = vsrc[3];

        float ss = x0.x*x0.x + x0.y*x0.y + x0.z*x0.z + x0.w*x0.w
                 + x1.x*x1.x + x1.y*x1.y + x1.z*x1.z + x1.w*x1.w
                 + x2.x*x2.x + x2.y*x2.y + x2.z*x2.z + x2.w*x2.w
                 + x3.x*x3.x + x3.y*x3.y + x3.z*x3.z + x3.w*x3.w;
        ss += __shfl_xor(ss, 1);
        ss += __shfl_xor(ss, 2);
        float nrm = sqrtf(ss);
        float rn = 1.f / fmaxf(nrm, 1e-12f);

        float4 k0 = make_float4(x0.x*rn, x0.y*rn, x0.z*rn, x0.w*rn);
        float4 k1 = make_float4(x1.x*rn, x1.y*rn, x1.z*rn, x1.w*rn);
        float4 k2 = make_float4(x2.x*rn, x2.y*rn, x2.z*rn, x2.w*rn);
        float4 k3 = make_float4(x3.x*rn, x3.y*rn, x3.z*rn, x3.w*rn);
        *(uint4*)&KV[tok * QS_ + q4 * 16]     = pack8(k0, k1);
        *(uint4*)&KV[tok * QS_ + q4 * 16 + 8] = pack8(k2, k3);

        vpk[p][0] = pk2(y0.x, y0.y); vpk[p][1] = pk2(y0.z, y0.w);
        vpk[p][2] = pk2(y1.x, y1.y); vpk[p][3] = pk2(y1.z, y1.w);
        vpk[p][4] = pk2(y2.x, y2.y); vpk[p][5] = pk2(y2.z, y2.w);
        vpk[p][6] = pk2(y3.x, y3.y); vpk[p][7] = pk2(y3.z, y3.w);

        if (p == 0 && q4 == 0) bounds[tok] = nrm * 0.125f;
    }
    __syncthreads();

    const int lane = tid & 63;
    const int w = tid >> 6;
    const int lm = lane & 15;
    const int lq = lane >> 4;

    const int   tq  = tkv[w * 16 + lm];
    const float bnd = bounds[w * 16 + lm];
    const float bl2 = bnd * LOG2E;

    // ---- S^T = K * Q^T ----
    const short8 bq0 = *(const short8*)&KV[(w * 16 + lm) * QS_ + lq * 8];
    const short8 bq1 = *(const short8*)&KV[(w * 16 + lm) * QS_ + 32 + lq * 8];
    floatx4 C[8];
    #pragma unroll
    for (int nt = 0; nt < 8; nt++) {
        const short8 a0 = *(const short8*)&KV[(nt * 16 + lm) * QS_ + lq * 8];
        const short8 a1 = *(const short8*)&KV[(nt * 16 + lm) * QS_ + 32 + lq * 8];
        floatx4 c = {0.f, 0.f, 0.f, 0.f};
        c = __builtin_amdgcn_mfma_f32_16x16x32_bf16(a0, bq0, c, 0, 0, 0);
        c = __builtin_amdgcn_mfma_f32_16x16x32_bf16(a1, bq1, c, 0, 0, 0);
        C[nt] = c;
    }

    // ---- mask + exp -> P in registers as x16 A-frags ----
    float lsum = 0.f, ns = 0.f;
    short4v pa[8];
    #pragma unroll
    for (int nt = 0; nt < 8; nt++) {
        int4 tki = *(const int4*)&tkv[nt * 16 + lq * 4];
        float p0 = (tki.x < tq) ? exp2f((C[nt][0] - 1.f) * bl2) : 0.f;
        float p1 = (tki.y < tq) ? exp2f((C[nt][1] - 1.f) * bl2) : 0.f;
        float p2 = (tki.z < tq) ? exp2f((C[nt][2] - 1.f) * bl2) : 0.f;
        float p3 = (tki.w < tq) ? exp2f((C[nt][3] - 1.f) * bl2) : 0.f;
        ns += (tki.x == tq) ? 1.f : 0.f;
        ns += (tki.y == tq) ? 1.f : 0.f;
        ns += (tki.z == tq) ? 1.f : 0.f;
        ns += (tki.w == tq) ? 1.f : 0.f;
        lsum += (p0 + p1) + (p2 + p3);
        pa[nt] = mk4(pk2(p0, p1), pk2(p2, p3));
    }
    lsum += __shfl_xor(lsum, 16);
    lsum += __shfl_xor(lsum, 32);
    ns   += __shfl_xor(ns, 16);
    ns   += __shfl_xor(ns, 32);
    __syncthreads();

    // ---- restage V^T over K region ----
    {
        unsigned* VT = (unsigned*)KV;
        const int par = stok & 1;
        #pragma unroll
        for (int p = 0; p < 2; p++) {
            int pd = p * 32 + (stok >> 1);
            int pdw = pd ^ (q4 << 3);
            #pragma unroll
            for (int i = 0; i < 8; i++) {
                unsigned mine = vpk[p][i];
                unsigned theirs = (unsigned)__shfl_xor((int)mine, 4);
                unsigned outw = par ? ((theirs >> 16) | (mine & 0xFFFF0000u))
                                    : ((mine & 0xFFFFu) | (theirs << 16));
                VT[(q4 * 16 + 2 * i + par) * VTS_ + pdw] = outw;
            }
        }
    }
    __syncthreads();

    // ---- PV ----
    const unsigned* VT = (const unsigned*)KV;
    floatx4 O[4];
    #pragma unroll
    for (int nt2 = 0; nt2 < 4; nt2++) O[nt2] = floatx4{0.f, 0.f, 0.f, 0.f};
    #pragma unroll
    for (int kt = 0; kt < 8; kt++) {
        #pragma unroll
        for (int nt2 = 0; nt2 < 4; nt2++) {
            const short4v vb = *(const short4v*)&VT[(nt2 * 16 + lm) * VTS_
                                + ((kt ^ nt2) * 8 + lq * 2)];
            O[nt2] = __builtin_amdgcn_mfma_f32_16x16x16bf16_1k(pa[kt], vb, O[nt2], 0, 0, 0);
        }
    }

    // ---- epilogue (sorted-order, fully coalesced stores) ----
    const size_t oBaseBH = (size_t)(b * H_ + h) * S_;
    const int spB = (cc & 63) * 64;       // sorted position base within (b,h)
    #pragma unroll
    for (int r = 0; r < 4; r++) {
        int qrow = w * 16 + lq * 4 + r;
        int pos = tkv[qrow];
        float s = __shfl(lsum, lq * 4 + r);
        float invl;
        if (s > 0.f) {
            invl = 1.f / s;
        } else {
            invl = 1.f;
            #pragma unroll
            for (int nt2 = 0; nt2 < 4; nt2++)
                O[nt2][r] = v[(size_t)(b * S_ + pos) * 64 + nt2 * 16 + lm];
        }
        #pragma unroll
        for (int nt2 = 0; nt2 < 4; nt2++)
            Ps[qrow * PS_ + nt2 * 16 + lm] = f2bf1(O[nt2][r] * invl);
    }
    if (lq == 0) {
        float lse = (lsum > 0.f) ? (bnd + log2f(lsum) * LN2)
                                 : (-50000.f + logf(ns));
        lse_u[oBaseBH + spB + w * 16 + lm] = lse;   // coalesced 64B per wave
    }
    {
        int rrow = lane >> 2;
        int seg = lane & 3;
        int qrow = w * 16 + rrow;
        uint4 u0 = *(uint4*)&Ps[qrow * PS_ + seg * 16];
        uint4 u1 = *(uint4*)&Ps[qrow * PS_ + seg * 16 + 8];
        unsigned short* dst = ou + (oBaseBH + spB + qrow) * 64 + seg * 16;
        *(uint4*)dst = u0;                           // wave covers 2 KB contiguous
        *(uint4*)(dst + 8) = u1;
    }
}

// ---------------- K4: combine hash rounds (gather via undo-sort) ----------------
__global__ void combine_kernel(const unsigned short* __restrict__ ou,
                               const float* __restrict__ lse_u,
                               const int* __restrict__ ud,
                               float* __restrict__ out) {
    int idx = blockIdx.x * 256 + threadIdx.x;
    int f4 = idx & 15;
    int t = (idx >> 4) & (S_ - 1);
    int b = idx >> 16;

    int pp[H_];
    float le[H_];
    float m = -3.4e38f;
    #pragma unroll
    for (int h = 0; h < H_; h++) {
        size_t sl = (size_t)(b * H_ + h) * S_;
        int p = ud[sl + t];
        pp[h] = p;
        le[h] = lse_u[sl + p];
        m = fmaxf(m, le[h]);
    }
    float s = 0.f, e[H_];
    #pragma unroll
    for (int h = 0; h < H_; h++) {
        e[h] = exp2f((le[h] - m) * LOG2E);
        s += e[h];
    }
    float4 o = make_float4(0.f, 0.f, 0.f, 0.f);
    #pragma unroll
    for (int h = 0; h < H_; h++) {
        uint2 u = *(const uint2*)(ou + ((size_t)((b * H_ + h) * S_ + pp[h])) * 64 + f4 * 4);
        o.x += e[h] * bf2f((unsigned short)(u.x & 0xFFFFu));
        o.y += e[h] * bf2f((unsigned short)(u.x >> 16));
        o.z += e[h] * bf2f((unsigned short)(u.y & 0xFFFFu));
        o.w += e[h] * bf2f((unsigned short)(u.y >> 16));
    }
    float inv = 1.f / s;
    ((float4*)out)[idx] = make_float4(o.x * inv, o.y * inv, o.z * inv, o.w * inv);
}

extern "C" void kernel_launch(void* const* d_in, const int* in_sizes, int n_in,
                              void* d_out, int out_size, void* d_ws, size_t ws_size,
                              hipStream_t stream) {
    const float* qk  = (const float*)d_in[0];
    const float* v   = (const float*)d_in[1];
    const float* rot = (const float*)d_in[2];
    float* out = (float*)d_out;

    char* ws = (char*)d_ws;
    int* bucket  = (int*)(ws);                       // 2 MB; reused as undo
    int* st      = (int*)(ws + 2097152);
    float* lse_u = (float*)(ws + 4194304);
    unsigned short* ou = (unsigned short*)(ws + 6291456);   // bf16, 67 MB
    int* undo = bucket;

    hash_kernel<<<dim3(B_ * H_ * (S_ / 512)), dim3(256), 0, stream>>>(qk, rot, bucket);
    sort_kernel<<<dim3(B_ * H_), dim3(256), 0, stream>>>(bucket, st, undo);
    attn_kernel<<<dim3(B_ * CHUNKS_), dim3(256), 0, stream>>>(qk, v, st, ou, lse_u);
    combine_kernel<<<dim3((B_ * S_ * 16) / 256), dim3(256), 0, stream>>>(ou, lse_u, undo, out);
}

// Round 6
// 202.223 us; speedup vs baseline: 1.1079x; 1.0228x over previous
//
#include <hip/hip_runtime.h>
#include <hip/hip_bf16.h>

#define B_ 16
#define S_ 4096
#define D_ 64
#define H_ 8
#define NB_ 64          // n_buckets
#define M_ 64           // bucket_size
#define CHUNKS_ 512     // per batch = H_*NB_
#define LOG2E 1.4426950408889634f
#define LN2 0.6931471805599453f

#define QS_ 72          // K LDS row stride (shorts)
#define VTS_ 68         // V^T row stride (dwords)
#define PS_ 72          // O-transpose staging row stride (shorts)

typedef short short8 __attribute__((ext_vector_type(8)));
typedef short short4v __attribute__((ext_vector_type(4)));
typedef float floatx4 __attribute__((ext_vector_type(4)));

__device__ __forceinline__ float bf2f(unsigned short s) {
    return __uint_as_float(((unsigned int)s) << 16);
}
__device__ __forceinline__ unsigned pk2(float a, float b) {
    __hip_bfloat162 h = __float22bfloat162_rn(make_float2(a, b));
    return *(unsigned*)&h;
}
__device__ __forceinline__ unsigned short f2bf1(float x) {
    return (unsigned short)pk2(x, x);
}
__device__ __forceinline__ uint4 pack8(float4 a, float4 b) {
    uint4 u;
    u.x = pk2(a.x, a.y); u.y = pk2(a.z, a.w);
    u.z = pk2(b.x, b.y); u.w = pk2(b.z, b.w);
    return u;
}
__device__ __forceinline__ short4v mk4(unsigned lo, unsigned hi) {
    uint2 t = make_uint2(lo, hi);
    return *(short4v*)&t;
}

// ---------------- K1: hashing, i-sliced (round-12 version, unchanged) ----------------
__global__ void __launch_bounds__(256)
hash_kernel(const float* __restrict__ qk,
            const float* __restrict__ rot,
            int* __restrict__ bucket) {
    int bh = blockIdx.x >> 3;      // (b*H + h)
    int tc = blockIdx.x & 7;       // 512-token chunk
    int h = bh & 7;
    int b = bh >> 3;

    __shared__ float rl[64 * 32];
    #pragma unroll
    for (int k = 0; k < 8; k++) {
        int e = k * 256 + threadIdx.x;
        rl[e] = rot[(e >> 5) * (H_ * 32) + h * 32 + (e & 31)];
    }
    __syncthreads();

    const int g = threadIdx.x >> 1;        // 0..127 token group
    const int s = threadIdx.x & 1;         // i-slice (cols s*16..s*16+15)
    const int s16 = s * 16;
    const int t0 = tc * 512 + g;           // tokens t0 + 128*j, j=0..3

    const float4* qr0 = (const float4*)(qk + ((size_t)(b * S_ + t0)) * D_);
    const float4* qr1 = (const float4*)(qk + ((size_t)(b * S_ + t0 + 128)) * D_);
    const float4* qr2 = (const float4*)(qk + ((size_t)(b * S_ + t0 + 256)) * D_);
    const float4* qr3 = (const float4*)(qk + ((size_t)(b * S_ + t0 + 384)) * D_);

    float acc[4][16];
    #pragma unroll
    for (int u = 0; u < 4; u++)
        #pragma unroll
        for (int i = 0; i < 16; i++) acc[u][i] = 0.f;

    for (int k = 0; k < 16; k++) {
        float4 x0 = qr0[k];
        float4 x1 = qr1[k];
        float4 x2 = qr2[k];
        float4 x3 = qr3[k];
        const float* r0 = &rl[(4 * k + 0) * 32 + s16];
        const float* r1 = &rl[(4 * k + 1) * 32 + s16];
        const float* r2 = &rl[(4 * k + 2) * 32 + s16];
        const float* r3 = &rl[(4 * k + 3) * 32 + s16];
        #pragma unroll
        for (int i = 0; i < 16; i++) {
            float a0 = r0[i], a1 = r1[i], a2 = r2[i], a3 = r3[i];
            acc[0][i] += x0.x * a0 + x0.y * a1 + x0.z * a2 + x0.w * a3;
            acc[1][i] += x1.x * a0 + x1.y * a1 + x1.z * a2 + x1.w * a3;
            acc[2][i] += x2.x * a0 + x2.y * a1 + x2.z * a2 + x2.w * a3;
            acc[3][i] += x3.x * a0 + x3.y * a1 + x3.z * a2 + x3.w * a3;
        }
    }

    #pragma unroll
    for (int u = 0; u < 4; u++) {
        float best = acc[u][0];
        int bi = s16;
        #pragma unroll
        for (int i = 1; i < 16; i++)
            if (acc[u][i] > best) { best = acc[u][i]; bi = s16 + i; }
        #pragma unroll
        for (int i = 0; i < 16; i++) {
            float nv = -acc[u][i];
            if (nv > best) { best = nv; bi = 32 + s16 + i; }
        }
        // combine the two slices; keep earliest index on exact ties
        float ov = __shfl_xor(best, 1);
        int obi = __shfl_xor(bi, 1);
        if (ov > best || (ov == best && obi < bi)) { best = ov; bi = obi; }
        if (s == 0) bucket[bh * S_ + t0 + 128 * u] = bi;
    }
}

// ---------------- K2: parallel stable counting sort (+undo), round-12 unchanged ----------------
__global__ void __launch_bounds__(256)
sort_kernel(const int* __restrict__ bucket,
            int* __restrict__ st,
            int* __restrict__ ud) {
    const int bh = blockIdx.x;
    const int t = threadIdx.x;
    __shared__ int bl[S_];             // 16 KB
    __shared__ int stl[S_];            // 16 KB (sorted tokens, coalesced dump)
    __shared__ int cnt[256 * 64];      // 64 KB: cnt[group*64 + bucket]
    __shared__ int qsum[64 * 4];       // per-bucket quarter sums
    __shared__ int tot[64];
    __shared__ int start[64];

    const int base = bh * S_;
    #pragma unroll
    for (int i = 0; i < 16; i++) bl[i * 256 + t] = bucket[base + i * 256 + t];
    #pragma unroll
    for (int i = 0; i < 64; i++) cnt[t * 64 + i] = 0;
    __syncthreads();

    // A: per-group histogram (serial 16)
    #pragma unroll
    for (int j = 0; j < 16; j++) cnt[t * 64 + bl[t * 16 + j]]++;
    __syncthreads();

    // B1: quarter sums
    {
        const int bk = t & 63, q = t >> 6;
        int s = 0;
        for (int g = q * 64; g < q * 64 + 64; g++) s += cnt[g * 64 + bk];
        qsum[bk * 4 + q] = s;
    }
    __syncthreads();

    // B2: bucket totals + global starts
    if (t < 64) tot[t] = qsum[t * 4] + qsum[t * 4 + 1] + qsum[t * 4 + 2] + qsum[t * 4 + 3];
    __syncthreads();
    if (t == 0) {
        int run = 0;
        for (int bk = 0; bk < 64; bk++) { start[bk] = run; run += tot[bk]; }
    }
    __syncthreads();

    // B3: exclusive running prefix (bucket-major, group-minor)
    {
        const int bk = t & 63, q = t >> 6;
        int run = start[bk];
        for (int qq = 0; qq < 4; qq++) if (qq < q) run += qsum[bk * 4 + qq];
        for (int g = q * 64; g < q * 64 + 64; g++) {
            int c = cnt[g * 64 + bk];
            cnt[g * 64 + bk] = run;
            run += c;
        }
    }
    __syncthreads();

    // C: stable placement into LDS; record inverse in bl
    #pragma unroll
    for (int j = 0; j < 16; j++) {
        int tok = t * 16 + j;
        int bk = bl[tok];
        int p = cnt[t * 64 + bk]++;
        stl[p] = tok;
        bl[tok] = p;
    }
    __syncthreads();

    // D: coalesced dumps
    #pragma unroll
    for (int i = 0; i < 16; i++) {
        st[base + i * 256 + t] = stl[i * 256 + t];
        ud[base + i * 256 + t] = bl[i * 256 + t];
    }
}

// ---------------- K3: MFMA chunked attention ----------------
// Round 13: VALU-instruction diet on the proven round-3 structure.
// Evidence: 80.5us @ 78% VALUBusy, 5 waves/SIMD -> ~2300 VALU instr/thread,
// ~4x the visible source math => libcall expansion (precise exp2f/sqrtf/div).
// Changes: (1) hardware transcendentals (v_exp/v_sqrt/v_rcp/v_log, ~1 ULP --
// drift far below bf16 output quantization); (2) lazy ns: self-count moved
// out of the hot loop into the rare lsum<=0 branch (serial 128-scan of tkv).
__global__ void __launch_bounds__(256, 5)
attn_kernel(const float* __restrict__ qk,
            const float* __restrict__ v,
            const int* __restrict__ st,
            unsigned short* __restrict__ ou,   // bf16 (B,H,S,D) SORTED order
            float* __restrict__ lse_u) {       // (B,H,S) SORTED order
    const int tid = threadIdx.x;
    const int gid = blockIdx.x;
    const int gc = (gid & 7) * 1024 + (gid >> 3);   // XCD-contiguous global chunk
    const int b = gc >> 9;
    const int cc = gc & 511;
    const int prev = (cc - 1) & 511;
    const int h = cc >> 6;

    __shared__ alignas(16) unsigned short KV[128 * QS_];  // K rows, then V^T
    __shared__ alignas(16) unsigned short Ps[64 * PS_];   // O transpose staging
    __shared__ int tkv[128];
    __shared__ float bounds[64];

    const int stBase = b * (CHUNKS_ * M_);
    if (tid < 128) tkv[tid] = st[stBase + (tid < 64 ? cc : prev) * 64 + (tid & 63)];
    __syncthreads();

    const int stok = tid >> 2;                 // 0..63 (token within pass)
    const int q4 = tid & 3;                    // 16-feature slice

    // ---- stage normalized K; hold V (packed bf16) in regs ----
    unsigned vpk[2][8];
    #pragma unroll
    for (int p = 0; p < 2; p++) {
        int tok = p * 64 + stok;
        int pos = tkv[tok];
        const float4* src = (const float4*)(qk + (size_t)(b * S_ + pos) * 64) + q4 * 4;
        float4 x0 = src[0], x1 = src[1], x2 = src[2], x3 = src[3];
        const float4* vsrc = (const float4*)(v + (size_t)(b * S_ + pos) * 64) + q4 * 4;
        float4 y0 = vsrc[0], y1 = vsrc[1], y2 = vsrc[2], y3 = vsrc[3];

        float ss = x0.x*x0.x + x0.y*x0.y + x0.z*x0.z + x0.w*x0.w
                 + x1.x*x1.x + x1.y*x1.y + x1.z*x1.z + x1.w*x1.w
                 + x2.x*x2.x + x2.y*x2.y + x2.z*x2.z + x2.w*x2.w
                 + x3.x*x3.x + x3.y*x3.y + x3.z*x3.z + x3.w*x3.w;
        ss += __shfl_xor(ss, 1);
        ss += __shfl_xor(ss, 2);
        float nrm = __builtin_amdgcn_sqrtf(ss);
        float rn = __builtin_amdgcn_rcpf(fmaxf(nrm, 1e-12f));

        float4 k0 = make_float4(x0.x*rn, x0.y*rn, x0.z*rn, x0.w*rn);
        float4 k1 = make_float4(x1.x*rn, x1.y*rn, x1.z*rn, x1.w*rn);
        float4 k2 = make_float4(x2.x*rn, x2.y*rn, x2.z*rn, x2.w*rn);
        float4 k3 = make_float4(x3.x*rn, x3.y*rn, x3.z*rn, x3.w*rn);
        *(uint4*)&KV[tok * QS_ + q4 * 16]     = pack8(k0, k1);
        *(uint4*)&KV[tok * QS_ + q4 * 16 + 8] = pack8(k2, k3);

        vpk[p][0] = pk2(y0.x, y0.y); vpk[p][1] = pk2(y0.z, y0.w);
        vpk[p][2] = pk2(y1.x, y1.y); vpk[p][3] = pk2(y1.z, y1.w);
        vpk[p][4] = pk2(y2.x, y2.y); vpk[p][5] = pk2(y2.z, y2.w);
        vpk[p][6] = pk2(y3.x, y3.y); vpk[p][7] = pk2(y3.z, y3.w);

        if (p == 0 && q4 == 0) bounds[tok] = nrm * 0.125f;
    }
    __syncthreads();

    const int lane = tid & 63;
    const int w = tid >> 6;
    const int lm = lane & 15;
    const int lq = lane >> 4;

    const int   tq  = tkv[w * 16 + lm];
    const float bnd = bounds[w * 16 + lm];
    const float bl2 = bnd * LOG2E;

    // ---- S^T = K * Q^T ----
    const short8 bq0 = *(const short8*)&KV[(w * 16 + lm) * QS_ + lq * 8];
    const short8 bq1 = *(const short8*)&KV[(w * 16 + lm) * QS_ + 32 + lq * 8];
    floatx4 C[8];
    #pragma unroll
    for (int nt = 0; nt < 8; nt++) {
        const short8 a0 = *(const short8*)&KV[(nt * 16 + lm) * QS_ + lq * 8];
        const short8 a1 = *(const short8*)&KV[(nt * 16 + lm) * QS_ + 32 + lq * 8];
        floatx4 c = {0.f, 0.f, 0.f, 0.f};
        c = __builtin_amdgcn_mfma_f32_16x16x32_bf16(a0, bq0, c, 0, 0, 0);
        c = __builtin_amdgcn_mfma_f32_16x16x32_bf16(a1, bq1, c, 0, 0, 0);
        C[nt] = c;
    }

    // ---- mask + exp -> P in registers as x16 A-frags (ns computed lazily) ----
    float lsum = 0.f;
    short4v pa[8];
    #pragma unroll
    for (int nt = 0; nt < 8; nt++) {
        int4 tki = *(const int4*)&tkv[nt * 16 + lq * 4];
        float p0 = (tki.x < tq) ? __builtin_amdgcn_exp2f((C[nt][0] - 1.f) * bl2) : 0.f;
        float p1 = (tki.y < tq) ? __builtin_amdgcn_exp2f((C[nt][1] - 1.f) * bl2) : 0.f;
        float p2 = (tki.z < tq) ? __builtin_amdgcn_exp2f((C[nt][2] - 1.f) * bl2) : 0.f;
        float p3 = (tki.w < tq) ? __builtin_amdgcn_exp2f((C[nt][3] - 1.f) * bl2) : 0.f;
        lsum += (p0 + p1) + (p2 + p3);
        pa[nt] = mk4(pk2(p0, p1), pk2(p2, p3));
    }
    lsum += __shfl_xor(lsum, 16);
    lsum += __shfl_xor(lsum, 32);
    __syncthreads();

    // ---- restage V^T over K region ----
    {
        unsigned* VT = (unsigned*)KV;
        const int par = stok & 1;
        #pragma unroll
        for (int p = 0; p < 2; p++) {
            int pd = p * 32 + (stok >> 1);
            int pdw = pd ^ (q4 << 3);
            #pragma unroll
            for (int i = 0; i < 8; i++) {
                unsigned mine = vpk[p][i];
                unsigned theirs = (unsigned)__shfl_xor((int)mine, 4);
                unsigned outw = par ? ((theirs >> 16) | (mine & 0xFFFF0000u))
                                    : ((mine & 0xFFFFu) | (theirs << 16));
                VT[(q4 * 16 + 2 * i + par) * VTS_ + pdw] = outw;
            }
        }
    }
    __syncthreads();

    // ---- PV ----
    const unsigned* VT = (const unsigned*)KV;
    floatx4 O[4];
    #pragma unroll
    for (int nt2 = 0; nt2 < 4; nt2++) O[nt2] = floatx4{0.f, 0.f, 0.f, 0.f};
    #pragma unroll
    for (int kt = 0; kt < 8; kt++) {
        #pragma unroll
        for (int nt2 = 0; nt2 < 4; nt2++) {
            const short4v vb = *(const short4v*)&VT[(nt2 * 16 + lm) * VTS_
                                + ((kt ^ nt2) * 8 + lq * 2)];
            O[nt2] = __builtin_amdgcn_mfma_f32_16x16x16bf16_1k(pa[kt], vb, O[nt2], 0, 0, 0);
        }
    }

    // ---- epilogue (sorted-order, fully coalesced stores) ----
    const size_t oBaseBH = (size_t)(b * H_ + h) * S_;
    const int spB = (cc & 63) * 64;       // sorted position base within (b,h)
    #pragma unroll
    for (int r = 0; r < 4; r++) {
        int qrow = w * 16 + lq * 4 + r;
        int pos = tkv[qrow];
        float s = __shfl(lsum, lq * 4 + r);
        float invl;
        if (s > 0.f) {
            invl = __builtin_amdgcn_rcpf(s);
        } else {
            invl = 1.f;
            #pragma unroll
            for (int nt2 = 0; nt2 < 4; nt2++)
                O[nt2][r] = v[(size_t)(b * S_ + pos) * 64 + nt2 * 16 + lm];
        }
        #pragma unroll
        for (int nt2 = 0; nt2 < 4; nt2++)
            Ps[qrow * PS_ + nt2 * 16 + lm] = f2bf1(O[nt2][r] * invl);
    }
    if (lq == 0) {
        float lse;
        if (lsum > 0.f) {
            lse = bnd + __builtin_amdgcn_logf(lsum) * LN2;
        } else {
            // rare: this row is the window's minimum position; count self-matches
            float nsf = 0.f;
            for (int j = 0; j < 128; j++) nsf += (tkv[j] == tq) ? 1.f : 0.f;
            lse = -50000.f + logf(nsf);
        }
        lse_u[oBaseBH + spB + w * 16 + lm] = lse;   // coalesced 64B per wave
    }
    {
        int rrow = lane >> 2;
        int seg = lane & 3;
        int qrow = w * 16 + rrow;
        uint4 u0 = *(uint4*)&Ps[qrow * PS_ + seg * 16];
        uint4 u1 = *(uint4*)&Ps[qrow * PS_ + seg * 16 + 8];
        unsigned short* dst = ou + (oBaseBH + spB + qrow) * 64 + seg * 16;
        *(uint4*)dst = u0;                           // wave covers 2 KB contiguous
        *(uint4*)(dst + 8) = u1;
    }
}

// ---------------- K4: combine hash rounds (gather via undo-sort) ----------------
__global__ void combine_kernel(const unsigned short* __restrict__ ou,
                               const float* __restrict__ lse_u,
                               const int* __restrict__ ud,
                               float* __restrict__ out) {
    int idx = blockIdx.x * 256 + threadIdx.x;
    int f4 = idx & 15;
    int t = (idx >> 4) & (S_ - 1);
    int b = idx >> 16;

    int pp[H_];
    float le[H_];
    float m = -3.4e38f;
    #pragma unroll
    for (int h = 0; h < H_; h++) {
        size_t sl = (size_t)(b * H_ + h) * S_;
        int p = ud[sl + t];
        pp[h] = p;
        le[h] = lse_u[sl + p];
        m = fmaxf(m, le[h]);
    }
    float s = 0.f, e[H_];
    #pragma unroll
    for (int h = 0; h < H_; h++) {
        e[h] = exp2f((le[h] - m) * LOG2E);
        s += e[h];
    }
    float4 o = make_float4(0.f, 0.f, 0.f, 0.f);
    #pragma unroll
    for (int h = 0; h < H_; h++) {
        uint2 u = *(const uint2*)(ou + ((size_t)((b * H_ + h) * S_ + pp[h])) * 64 + f4 * 4);
        o.x += e[h] * bf2f((unsigned short)(u.x & 0xFFFFu));
        o.y += e[h] * bf2f((unsigned short)(u.x >> 16));
        o.z += e[h] * bf2f((unsigned short)(u.y & 0xFFFFu));
        o.w += e[h] * bf2f((unsigned short)(u.y >> 16));
    }
    float inv = 1.f / s;
    ((float4*)out)[idx] = make_float4(o.x * inv, o.y * inv, o.z * inv, o.w * inv);
}

extern "C" void kernel_launch(void* const* d_in, const int* in_sizes, int n_in,
                              void* d_out, int out_size, void* d_ws, size_t ws_size,
                              hipStream_t stream) {
    const float* qk  = (const float*)d_in[0];
    const float* v   = (const float*)d_in[1];
    const float* rot = (const float*)d_in[2];
    float* out = (float*)d_out;

    char* ws = (char*)d_ws;
    int* bucket  = (int*)(ws);                       // 2 MB; reused as undo
    int* st      = (int*)(ws + 2097152);
    float* lse_u = (float*)(ws + 4194304);
    unsigned short* ou = (unsigned short*)(ws + 6291456);   // bf16, 67 MB
    int* undo = bucket;

    hash_kernel<<<dim3(B_ * H_ * (S_ / 512)), dim3(256), 0, stream>>>(qk, rot, bucket);
    sort_kernel<<<dim3(B_ * H_), dim3(256), 0, stream>>>(bucket, st, undo);
    attn_kernel<<<dim3(B_ * CHUNKS_), dim3(256), 0, stream>>>(qk, v, st, ou, lse_u);
    combine_kernel<<<dim3((B_ * S_ * 16) / 256), dim3(256), 0, stream>>>(ou, lse_u, undo, out);
}

// Round 7
// 201.401 us; speedup vs baseline: 1.1124x; 1.0041x over previous
//
#include <hip/hip_runtime.h>
#include <hip/hip_bf16.h>

#define B_ 16
#define S_ 4096
#define D_ 64
#define H_ 8
#define NB_ 64          // n_buckets
#define M_ 64           // bucket_size
#define CHUNKS_ 512     // per batch = H_*NB_
#define LOG2E 1.4426950408889634f
#define LN2 0.6931471805599453f

#define QS_ 72          // K LDS row stride (shorts)
#define VTS_ 68         // V^T row stride (dwords)
#define PS_ 72          // O-transpose staging row stride (shorts)

typedef short short8 __attribute__((ext_vector_type(8)));
typedef short short4v __attribute__((ext_vector_type(4)));
typedef float floatx4 __attribute__((ext_vector_type(4)));

__device__ __forceinline__ float bf2f(unsigned short s) {
    return __uint_as_float(((unsigned int)s) << 16);
}
// Round 14: single-instruction packed f32->bf16 (RNE) via gfx950's
// v_cvt_pk_bf16_f32. All 64 pack sites/thread funnel through here; the
// HIP __float22bfloat162_rn path was the prime suspect for the ~1000
// unexplained VALU instrs/thread (software RNE expansion).
__device__ __forceinline__ unsigned pk2(float a, float b) {
    unsigned r;
    asm("v_cvt_pk_bf16_f32 %0, %1, %2" : "=v"(r) : "v"(a), "v"(b));
    return r;
}
__device__ __forceinline__ unsigned short f2bf1(float x) {
    return (unsigned short)pk2(x, x);
}
__device__ __forceinline__ uint4 pack8(float4 a, float4 b) {
    uint4 u;
    u.x = pk2(a.x, a.y); u.y = pk2(a.z, a.w);
    u.z = pk2(b.x, b.y); u.w = pk2(b.z, b.w);
    return u;
}
__device__ __forceinline__ short4v mk4(unsigned lo, unsigned hi) {
    uint2 t = make_uint2(lo, hi);
    return *(short4v*)&t;
}

// ---------------- K1: hashing, i-sliced (round-12 version, unchanged) ----------------
__global__ void __launch_bounds__(256)
hash_kernel(const float* __restrict__ qk,
            const float* __restrict__ rot,
            int* __restrict__ bucket) {
    int bh = blockIdx.x >> 3;      // (b*H + h)
    int tc = blockIdx.x & 7;       // 512-token chunk
    int h = bh & 7;
    int b = bh >> 3;

    __shared__ float rl[64 * 32];
    #pragma unroll
    for (int k = 0; k < 8; k++) {
        int e = k * 256 + threadIdx.x;
        rl[e] = rot[(e >> 5) * (H_ * 32) + h * 32 + (e & 31)];
    }
    __syncthreads();

    const int g = threadIdx.x >> 1;        // 0..127 token group
    const int s = threadIdx.x & 1;         // i-slice (cols s*16..s*16+15)
    const int s16 = s * 16;
    const int t0 = tc * 512 + g;           // tokens t0 + 128*j, j=0..3

    const float4* qr0 = (const float4*)(qk + ((size_t)(b * S_ + t0)) * D_);
    const float4* qr1 = (const float4*)(qk + ((size_t)(b * S_ + t0 + 128)) * D_);
    const float4* qr2 = (const float4*)(qk + ((size_t)(b * S_ + t0 + 256)) * D_);
    const float4* qr3 = (const float4*)(qk + ((size_t)(b * S_ + t0 + 384)) * D_);

    float acc[4][16];
    #pragma unroll
    for (int u = 0; u < 4; u++)
        #pragma unroll
        for (int i = 0; i < 16; i++) acc[u][i] = 0.f;

    for (int k = 0; k < 16; k++) {
        float4 x0 = qr0[k];
        float4 x1 = qr1[k];
        float4 x2 = qr2[k];
        float4 x3 = qr3[k];
        const float* r0 = &rl[(4 * k + 0) * 32 + s16];
        const float* r1 = &rl[(4 * k + 1) * 32 + s16];
        const float* r2 = &rl[(4 * k + 2) * 32 + s16];
        const float* r3 = &rl[(4 * k + 3) * 32 + s16];
        #pragma unroll
        for (int i = 0; i < 16; i++) {
            float a0 = r0[i], a1 = r1[i], a2 = r2[i], a3 = r3[i];
            acc[0][i] += x0.x * a0 + x0.y * a1 + x0.z * a2 + x0.w * a3;
            acc[1][i] += x1.x * a0 + x1.y * a1 + x1.z * a2 + x1.w * a3;
            acc[2][i] += x2.x * a0 + x2.y * a1 + x2.z * a2 + x2.w * a3;
            acc[3][i] += x3.x * a0 + x3.y * a1 + x3.z * a2 + x3.w * a3;
        }
    }

    #pragma unroll
    for (int u = 0; u < 4; u++) {
        float best = acc[u][0];
        int bi = s16;
        #pragma unroll
        for (int i = 1; i < 16; i++)
            if (acc[u][i] > best) { best = acc[u][i]; bi = s16 + i; }
        #pragma unroll
        for (int i = 0; i < 16; i++) {
            float nv = -acc[u][i];
            if (nv > best) { best = nv; bi = 32 + s16 + i; }
        }
        // combine the two slices; keep earliest index on exact ties
        float ov = __shfl_xor(best, 1);
        int obi = __shfl_xor(bi, 1);
        if (ov > best || (ov == best && obi < bi)) { best = ov; bi = obi; }
        if (s == 0) bucket[bh * S_ + t0 + 128 * u] = bi;
    }
}

// ---------------- K2: parallel stable counting sort (+undo) ----------------
// Round 14: B2's single-thread 64-iter serial prefix (≈3us of dependent LDS
// RMW on a 1-block/CU kernel) replaced by a 1-wave shfl_up scan (bit-exact).
__global__ void __launch_bounds__(256)
sort_kernel(const int* __restrict__ bucket,
            int* __restrict__ st,
            int* __restrict__ ud) {
    const int bh = blockIdx.x;
    const int t = threadIdx.x;
    __shared__ int bl[S_];             // 16 KB
    __shared__ int stl[S_];            // 16 KB (sorted tokens, coalesced dump)
    __shared__ int cnt[256 * 64];      // 64 KB: cnt[group*64 + bucket]
    __shared__ int qsum[64 * 4];       // per-bucket quarter sums
    __shared__ int tot[64];
    __shared__ int start[64];

    const int base = bh * S_;
    #pragma unroll
    for (int i = 0; i < 16; i++) bl[i * 256 + t] = bucket[base + i * 256 + t];
    #pragma unroll
    for (int i = 0; i < 64; i++) cnt[t * 64 + i] = 0;
    __syncthreads();

    // A: per-group histogram (serial 16)
    #pragma unroll
    for (int j = 0; j < 16; j++) cnt[t * 64 + bl[t * 16 + j]]++;
    __syncthreads();

    // B1: quarter sums
    {
        const int bk = t & 63, q = t >> 6;
        int s = 0;
        for (int g = q * 64; g < q * 64 + 64; g++) s += cnt[g * 64 + bk];
        qsum[bk * 4 + q] = s;
    }
    __syncthreads();

    // B2: bucket totals + global starts (wave-parallel exclusive scan)
    if (t < 64) tot[t] = qsum[t * 4] + qsum[t * 4 + 1] + qsum[t * 4 + 2] + qsum[t * 4 + 3];
    __syncthreads();
    if (t < 64) {
        int x = tot[t];
        #pragma unroll
        for (int d = 1; d < 64; d <<= 1) {
            int y = __shfl_up(x, d);
            if (t >= d) x += y;
        }
        start[t] = x - tot[t];     // exclusive prefix
    }
    __syncthreads();

    // B3: exclusive running prefix (bucket-major, group-minor)
    {
        const int bk = t & 63, q = t >> 6;
        int run = start[bk];
        for (int qq = 0; qq < 4; qq++) if (qq < q) run += qsum[bk * 4 + qq];
        for (int g = q * 64; g < q * 64 + 64; g++) {
            int c = cnt[g * 64 + bk];
            cnt[g * 64 + bk] = run;
            run += c;
        }
    }
    __syncthreads();

    // C: stable placement into LDS; record inverse in bl
    #pragma unroll
    for (int j = 0; j < 16; j++) {
        int tok = t * 16 + j;
        int bk = bl[tok];
        int p = cnt[t * 64 + bk]++;
        stl[p] = tok;
        bl[tok] = p;
    }
    __syncthreads();

    // D: coalesced dumps
    #pragma unroll
    for (int i = 0; i < 16; i++) {
        st[base + i * 256 + t] = stl[i * 256 + t];
        ud[base + i * 256 + t] = bl[i * 256 + t];
    }
}

// ---------------- K3: MFMA chunked attention ----------------
// Round 14: pk2 -> v_cvt_pk_bf16_f32 inline asm (64 pack sites/thread).
// Structure identical to round-13 (proven 74.8us).
__global__ void __launch_bounds__(256, 5)
attn_kernel(const float* __restrict__ qk,
            const float* __restrict__ v,
            const int* __restrict__ st,
            unsigned short* __restrict__ ou,   // bf16 (B,H,S,D) SORTED order
            float* __restrict__ lse_u) {       // (B,H,S) SORTED order
    const int tid = threadIdx.x;
    const int gid = blockIdx.x;
    const int gc = (gid & 7) * 1024 + (gid >> 3);   // XCD-contiguous global chunk
    const int b = gc >> 9;
    const int cc = gc & 511;
    const int prev = (cc - 1) & 511;
    const int h = cc >> 6;

    __shared__ alignas(16) unsigned short KV[128 * QS_];  // K rows, then V^T
    __shared__ alignas(16) unsigned short Ps[64 * PS_];   // O transpose staging
    __shared__ int tkv[128];
    __shared__ float bounds[64];

    const int stBase = b * (CHUNKS_ * M_);
    if (tid < 128) tkv[tid] = st[stBase + (tid < 64 ? cc : prev) * 64 + (tid & 63)];
    __syncthreads();

    const int stok = tid >> 2;                 // 0..63 (token within pass)
    const int q4 = tid & 3;                    // 16-feature slice

    // ---- stage normalized K; hold V (packed bf16) in regs ----
    unsigned vpk[2][8];
    #pragma unroll
    for (int p = 0; p < 2; p++) {
        int tok = p * 64 + stok;
        int pos = tkv[tok];
        const float4* src = (const float4*)(qk + (size_t)(b * S_ + pos) * 64) + q4 * 4;
        float4 x0 = src[0], x1 = src[1], x2 = src[2], x3 = src[3];
        const float4* vsrc = (const float4*)(v + (size_t)(b * S_ + pos) * 64) + q4 * 4;
        float4 y0 = vsrc[0], y1 = vsrc[1], y2 = vsrc[2], y3 = vsrc[3];

        float ss = x0.x*x0.x + x0.y*x0.y + x0.z*x0.z + x0.w*x0.w
                 + x1.x*x1.x + x1.y*x1.y + x1.z*x1.z + x1.w*x1.w
                 + x2.x*x2.x + x2.y*x2.y + x2.z*x2.z + x2.w*x2.w
                 + x3.x*x3.x + x3.y*x3.y + x3.z*x3.z + x3.w*x3.w;
        ss += __shfl_xor(ss, 1);
        ss += __shfl_xor(ss, 2);
        float nrm = __builtin_amdgcn_sqrtf(ss);
        float rn = __builtin_amdgcn_rcpf(fmaxf(nrm, 1e-12f));

        float4 k0 = make_float4(x0.x*rn, x0.y*rn, x0.z*rn, x0.w*rn);
        float4 k1 = make_float4(x1.x*rn, x1.y*rn, x1.z*rn, x1.w*rn);
        float4 k2 = make_float4(x2.x*rn, x2.y*rn, x2.z*rn, x2.w*rn);
        float4 k3 = make_float4(x3.x*rn, x3.y*rn, x3.z*rn, x3.w*rn);
        *(uint4*)&KV[tok * QS_ + q4 * 16]     = pack8(k0, k1);
        *(uint4*)&KV[tok * QS_ + q4 * 16 + 8] = pack8(k2, k3);

        vpk[p][0] = pk2(y0.x, y0.y); vpk[p][1] = pk2(y0.z, y0.w);
        vpk[p][2] = pk2(y1.x, y1.y); vpk[p][3] = pk2(y1.z, y1.w);
        vpk[p][4] = pk2(y2.x, y2.y); vpk[p][5] = pk2(y2.z, y2.w);
        vpk[p][6] = pk2(y3.x, y3.y); vpk[p][7] = pk2(y3.z, y3.w);

        if (p == 0 && q4 == 0) bounds[tok] = nrm * 0.125f;
    }
    __syncthreads();

    const int lane = tid & 63;
    const int w = tid >> 6;
    const int lm = lane & 15;
    const int lq = lane >> 4;

    const int   tq  = tkv[w * 16 + lm];
    const float bnd = bounds[w * 16 + lm];
    const float bl2 = bnd * LOG2E;

    // ---- S^T = K * Q^T ----
    const short8 bq0 = *(const short8*)&KV[(w * 16 + lm) * QS_ + lq * 8];
    const short8 bq1 = *(const short8*)&KV[(w * 16 + lm) * QS_ + 32 + lq * 8];
    floatx4 C[8];
    #pragma unroll
    for (int nt = 0; nt < 8; nt++) {
        const short8 a0 = *(const short8*)&KV[(nt * 16 + lm) * QS_ + lq * 8];
        const short8 a1 = *(const short8*)&KV[(nt * 16 + lm) * QS_ + 32 + lq * 8];
        floatx4 c = {0.f, 0.f, 0.f, 0.f};
        c = __builtin_amdgcn_mfma_f32_16x16x32_bf16(a0, bq0, c, 0, 0, 0);
        c = __builtin_amdgcn_mfma_f32_16x16x32_bf16(a1, bq1, c, 0, 0, 0);
        C[nt] = c;
    }

    // ---- mask + exp -> P in registers as x16 A-frags (ns computed lazily) ----
    float lsum = 0.f;
    short4v pa[8];
    #pragma unroll
    for (int nt = 0; nt < 8; nt++) {
        int4 tki = *(const int4*)&tkv[nt * 16 + lq * 4];
        float p0 = (tki.x < tq) ? __builtin_amdgcn_exp2f((C[nt][0] - 1.f) * bl2) : 0.f;
        float p1 = (tki.y < tq) ? __builtin_amdgcn_exp2f((C[nt][1] - 1.f) * bl2) : 0.f;
        float p2 = (tki.z < tq) ? __builtin_amdgcn_exp2f((C[nt][2] - 1.f) * bl2) : 0.f;
        float p3 = (tki.w < tq) ? __builtin_amdgcn_exp2f((C[nt][3] - 1.f) * bl2) : 0.f;
        lsum += (p0 + p1) + (p2 + p3);
        pa[nt] = mk4(pk2(p0, p1), pk2(p2, p3));
    }
    lsum += __shfl_xor(lsum, 16);
    lsum += __shfl_xor(lsum, 32);
    __syncthreads();

    // ---- restage V^T over K region ----
    {
        unsigned* VT = (unsigned*)KV;
        const int par = stok & 1;
        #pragma unroll
        for (int p = 0; p < 2; p++) {
            int pd = p * 32 + (stok >> 1);
            int pdw = pd ^ (q4 << 3);
            #pragma unroll
            for (int i = 0; i < 8; i++) {
                unsigned mine = vpk[p][i];
                unsigned theirs = (unsigned)__shfl_xor((int)mine, 4);
                unsigned outw = par ? ((theirs >> 16) | (mine & 0xFFFF0000u))
                                    : ((mine & 0xFFFFu) | (theirs << 16));
                VT[(q4 * 16 + 2 * i + par) * VTS_ + pdw] = outw;
            }
        }
    }
    __syncthreads();

    // ---- PV ----
    const unsigned* VT = (const unsigned*)KV;
    floatx4 O[4];
    #pragma unroll
    for (int nt2 = 0; nt2 < 4; nt2++) O[nt2] = floatx4{0.f, 0.f, 0.f, 0.f};
    #pragma unroll
    for (int kt = 0; kt < 8; kt++) {
        #pragma unroll
        for (int nt2 = 0; nt2 < 4; nt2++) {
            const short4v vb = *(const short4v*)&VT[(nt2 * 16 + lm) * VTS_
                                + ((kt ^ nt2) * 8 + lq * 2)];
            O[nt2] = __builtin_amdgcn_mfma_f32_16x16x16bf16_1k(pa[kt], vb, O[nt2], 0, 0, 0);
        }
    }

    // ---- epilogue (sorted-order, fully coalesced stores) ----
    const size_t oBaseBH = (size_t)(b * H_ + h) * S_;
    const int spB = (cc & 63) * 64;       // sorted position base within (b,h)
    #pragma unroll
    for (int r = 0; r < 4; r++) {
        int qrow = w * 16 + lq * 4 + r;
        int pos = tkv[qrow];
        float s = __shfl(lsum, lq * 4 + r);
        float invl;
        if (s > 0.f) {
            invl = __builtin_amdgcn_rcpf(s);
        } else {
            invl = 1.f;
            #pragma unroll
            for (int nt2 = 0; nt2 < 4; nt2++)
                O[nt2][r] = v[(size_t)(b * S_ + pos) * 64 + nt2 * 16 + lm];
        }
        #pragma unroll
        for (int nt2 = 0; nt2 < 4; nt2++)
            Ps[qrow * PS_ + nt2 * 16 + lm] = f2bf1(O[nt2][r] * invl);
    }
    if (lq == 0) {
        float lse;
        if (lsum > 0.f) {
            lse = bnd + __builtin_amdgcn_logf(lsum) * LN2;
        } else {
            // rare: this row is the window's minimum position; count self-matches
            float nsf = 0.f;
            for (int j = 0; j < 128; j++) nsf += (tkv[j] == tq) ? 1.f : 0.f;
            lse = -50000.f + logf(nsf);
        }
        lse_u[oBaseBH + spB + w * 16 + lm] = lse;   // coalesced 64B per wave
    }
    {
        int rrow = lane >> 2;
        int seg = lane & 3;
        int qrow = w * 16 + rrow;
        uint4 u0 = *(uint4*)&Ps[qrow * PS_ + seg * 16];
        uint4 u1 = *(uint4*)&Ps[qrow * PS_ + seg * 16 + 8];
        unsigned short* dst = ou + (oBaseBH + spB + qrow) * 64 + seg * 16;
        *(uint4*)dst = u0;                           // wave covers 2 KB contiguous
        *(uint4*)(dst + 8) = u1;
    }
}

// ---------------- K4: combine hash rounds (gather via undo-sort) ----------------
__global__ void combine_kernel(const unsigned short* __restrict__ ou,
                               const float* __restrict__ lse_u,
                               const int* __restrict__ ud,
                               float* __restrict__ out) {
    int idx = blockIdx.x * 256 + threadIdx.x;
    int f4 = idx & 15;
    int t = (idx >> 4) & (S_ - 1);
    int b = idx >> 16;

    int pp[H_];
    float le[H_];
    float m = -3.4e38f;
    #pragma unroll
    for (int h = 0; h < H_; h++) {
        size_t sl = (size_t)(b * H_ + h) * S_;
        int p = ud[sl + t];
        pp[h] = p;
        le[h] = lse_u[sl + p];
        m = fmaxf(m, le[h]);
    }
    float s = 0.f, e[H_];
    #pragma unroll
    for (int h = 0; h < H_; h++) {
        e[h] = exp2f((le[h] - m) * LOG2E);
        s += e[h];
    }
    float4 o = make_float4(0.f, 0.f, 0.f, 0.f);
    #pragma unroll
    for (int h = 0; h < H_; h++) {
        uint2 u = *(const uint2*)(ou + ((size_t)((b * H_ + h) * S_ + pp[h])) * 64 + f4 * 4);
        o.x += e[h] * bf2f((unsigned short)(u.x & 0xFFFFu));
        o.y += e[h] * bf2f((unsigned short)(u.x >> 16));
        o.z += e[h] * bf2f((unsigned short)(u.y & 0xFFFFu));
        o.w += e[h] * bf2f((unsigned short)(u.y >> 16));
    }
    float inv = 1.f / s;
    ((float4*)out)[idx] = make_float4(o.x * inv, o.y * inv, o.z * inv, o.w * inv);
}

extern "C" void kernel_launch(void* const* d_in, const int* in_sizes, int n_in,
                              void* d_out, int out_size, void* d_ws, size_t ws_size,
                              hipStream_t stream) {
    const float* qk  = (const float*)d_in[0];
    const float* v   = (const float*)d_in[1];
    const float* rot = (const float*)d_in[2];
    float* out = (float*)d_out;

    char* ws = (char*)d_ws;
    int* bucket  = (int*)(ws);                       // 2 MB; reused as undo
    int* st      = (int*)(ws + 2097152);
    float* lse_u = (float*)(ws + 4194304);
    unsigned short* ou = (unsigned short*)(ws + 6291456);   // bf16, 67 MB
    int* undo = bucket;

    hash_kernel<<<dim3(B_ * H_ * (S_ / 512)), dim3(256), 0, stream>>>(qk, rot, bucket);
    sort_kernel<<<dim3(B_ * H_), dim3(256), 0, stream>>>(bucket, st, undo);
    attn_kernel<<<dim3(B_ * CHUNKS_), dim3(256), 0, stream>>>(qk, v, st, ou, lse_u);
    combine_kernel<<<dim3((B_ * S_ * 16) / 256), dim3(256), 0, stream>>>(ou, lse_u, undo, out);
}